// Round 1
// baseline (4001.625 us; speedup 1.0000x reference)
//
#include <hip/hip_runtime.h>
#include <hip/hip_bf16.h>

// Problem constants (B,C_in,C_out,H,W) = (16,128,256,128,128)
constexpr int B  = 16;
constexpr int C  = 128;   // C_in for all convs; C_out of conv1/conv2
constexpr int H  = 128;
constexpr int W  = 128;
constexpr int CO = 256;   // downconv out channels
constexpr int HO = 64;
constexpr int WO = 64;

#define EPSV   1e-8f
#define SLOPE  0.2f

__device__ __forceinline__ float ldf(const float* p) { return *p; }
__device__ __forceinline__ float ldf(const __hip_bfloat16* p) { return __bfloat162float(*p); }

// ---------------------------------------------------------------------------
// Kernel 1: demod factors d[conv][b][o] = rsqrt(sum_{i,k}(w[o,i,k]*(s[b,i]+1))^2 + eps)
// grid = 2*B*C blocks, 128 threads (thread = input channel i)
// ---------------------------------------------------------------------------
__global__ __launch_bounds__(128) void demod_kernel(
    const float* __restrict__ w1, const float* __restrict__ w2,
    const float* __restrict__ s1, const float* __restrict__ s2,
    float* __restrict__ d)
{
    int bid  = blockIdx.x;          // conv*2048 + b*128 + o
    int conv = bid >> 11;
    int b    = (bid >> 7) & 15;
    int o    = bid & 127;
    const float* w = conv ? w2 : w1;
    const float* s = conv ? s2 : s1;
    int i = threadIdx.x;
    float sv = s[b * C + i] + 1.0f;
    const float* wp = w + (o * C + i) * 9;
    float sum = 0.f;
    #pragma unroll
    for (int k = 0; k < 9; ++k) { float t = wp[k] * sv; sum += t * t; }
    // reduce 128 values: per-wave shuffle, then cross-wave via LDS
    #pragma unroll
    for (int off = 32; off; off >>= 1) sum += __shfl_down(sum, off);
    __shared__ float red[2];
    if ((threadIdx.x & 63) == 0) red[threadIdx.x >> 6] = sum;
    __syncthreads();
    if (threadIdx.x == 0) d[bid] = rsqrtf(red[0] + red[1] + EPSV);
}

// ---------------------------------------------------------------------------
// Kernel 2: expand modulated weights  wm[conv][b][i][tap][o] (oc contiguous)
// total 2*16*128*9*128 = 4718592 elements
// ---------------------------------------------------------------------------
__global__ __launch_bounds__(256) void expand_kernel(
    const float* __restrict__ w1, const float* __restrict__ w2,
    const float* __restrict__ s1, const float* __restrict__ s2,
    const float* __restrict__ d, float* __restrict__ wm)
{
    int idx = blockIdx.x * 256 + threadIdx.x;   // grid sized exactly
    int o    = idx & 127;
    int tap  = (idx >> 7) % 9;
    int i    = (idx / 1152) & 127;
    int b    = (idx / 147456) & 15;
    int conv = idx / 2359296;
    const float* w = conv ? w2 : w1;
    const float* s = conv ? s2 : s1;
    wm[idx] = w[(o * C + i) * 9 + tap] * (s[b * C + i] + 1.0f)
            * d[(conv * B + b) * C + o];
}

// ---------------------------------------------------------------------------
// Kernel 3/4: 3x3 SAME conv, per-batch weights, + optional residual, leaky relu
// block = 256 threads; tile = 32 oc x (32h x 16w); 2 pixels/thread, 64 fp32 acc
// ---------------------------------------------------------------------------
template <typename Tin>
__global__ __launch_bounds__(256) void conv3x3_kernel(
    const Tin* __restrict__ in, const float* __restrict__ wm,
    const __hip_bfloat16* __restrict__ res, __hip_bfloat16* __restrict__ out)
{
    __shared__ float sIn[8][34][18];   // 8 ic x (32+2) x (16+2) halo tile
    __shared__ float sW[8][9][32];     // 8 ic x 9 taps x 32 oc

    int lin = blockIdx.x;
    int xt  = lin & 7;  lin >>= 3;     // 128/16 = 8 x-tiles
    int yt  = lin & 3;  lin >>= 2;     // 128/32 = 4 y-tiles
    int oct = lin & 3;  lin >>= 2;     // 128/32 = 4 oc-tiles
    int b   = lin;
    int x0 = xt * 16, y0 = yt * 32, oc0 = oct * 32;

    int tid = threadIdx.x;
    int tx = tid & 15, ty = tid >> 4;  // 16x16 threads, pixel pair (ty, ty+16)

    float acc0[32], acc1[32];
    #pragma unroll
    for (int o = 0; o < 32; ++o) { acc0[o] = 0.f; acc1[o] = 0.f; }

    const float* wmb = wm + b * (C * 9 * C);

    for (int ic0 = 0; ic0 < C; ic0 += 8) {
        __syncthreads();
        // stage input halo tile (8*34*18 = 4896 elems)
        for (int i = tid; i < 8 * 34 * 18; i += 256) {
            int ic  = i / 612;
            int rem = i - ic * 612;
            int r = rem / 18, c = rem - r * 18;
            int gh = y0 - 1 + r, gw = x0 - 1 + c;
            float v = 0.f;
            if ((unsigned)gh < (unsigned)H && (unsigned)gw < (unsigned)W)
                v = ldf(&in[((b * C + ic0 + ic) * H + gh) * W + gw]);
            sIn[ic][r][c] = v;
        }
        // stage weights (8*9*32 = 2304 elems, oc-contiguous -> coalesced)
        for (int i = tid; i < 8 * 9 * 32; i += 256) {
            int ic  = i / 288;
            int rem = i - ic * 288;
            int tap = rem >> 5, o = rem & 31;
            sW[ic][tap][o] = wmb[((ic0 + ic) * 9 + tap) * C + oc0 + o];
        }
        __syncthreads();

        for (int ic = 0; ic < 8; ++ic) {
            #pragma unroll
            for (int tap = 0; tap < 9; ++tap) {
                float in0 = sIn[ic][ty + tap / 3][tx + tap % 3];
                float in1 = sIn[ic][ty + 16 + tap / 3][tx + tap % 3];
                const float4* wp = (const float4*)&sW[ic][tap][0];
                #pragma unroll
                for (int o4 = 0; o4 < 8; ++o4) {
                    float4 w4 = wp[o4];
                    acc0[o4*4+0] += w4.x * in0;  acc1[o4*4+0] += w4.x * in1;
                    acc0[o4*4+1] += w4.y * in0;  acc1[o4*4+1] += w4.y * in1;
                    acc0[o4*4+2] += w4.z * in0;  acc1[o4*4+2] += w4.z * in1;
                    acc0[o4*4+3] += w4.w * in0;  acc1[o4*4+3] += w4.w * in1;
                }
            }
        }
    }

    int y = y0 + ty, x = x0 + tx;
    #pragma unroll
    for (int o = 0; o < 32; ++o) {
        int idx0 = ((b * C + oc0 + o) * H + y) * W + x;
        int idx1 = idx0 + 16 * W;
        float v0 = acc0[o], v1 = acc1[o];
        if (res) {
            v0 += __bfloat162float(res[idx0]);
            v1 += __bfloat162float(res[idx1]);
        }
        v0 = v0 >= 0.f ? v0 : SLOPE * v0;
        v1 = v1 >= 0.f ? v1 : SLOPE * v1;
        out[idx0] = __float2bfloat16(v0);
        out[idx1] = __float2bfloat16(v1);
    }
}

// ---------------------------------------------------------------------------
// Kernel 5: 4x4 stride-2 pad-1 conv + bias. out [16,256,64,64] fp32
// block = 256 threads; tile = 32 oc x (32h x 16w out); 2 px/thread
// ---------------------------------------------------------------------------
__global__ __launch_bounds__(256) void downconv_kernel(
    const __hip_bfloat16* __restrict__ in, const float* __restrict__ dw,
    const float* __restrict__ db, float* __restrict__ out)
{
    __shared__ float sIn[4][66][35];   // 4 ic x (2*32+2) x (2*16+2), col-padded to 35
    __shared__ float sW[4][16][32];    // 4 ic x 16 taps x 32 oc

    int lin = blockIdx.x;
    int xt  = lin & 3;  lin >>= 2;     // 64/16 = 4
    int yt  = lin & 1;  lin >>= 1;     // 64/32 = 2
    int oct = lin & 7;  lin >>= 3;     // 256/32 = 8
    int b   = lin;
    int x0 = xt * 16, y0 = yt * 32, oc0 = oct * 32;

    int tid = threadIdx.x;
    int tx = tid & 15, ty = tid >> 4;

    float acc0[32], acc1[32];
    #pragma unroll
    for (int o = 0; o < 32; ++o) { acc0[o] = 0.f; acc1[o] = 0.f; }

    for (int ic0 = 0; ic0 < C; ic0 += 4) {
        __syncthreads();
        // stage input (4*66*34 = 8976 elems)
        for (int i = tid; i < 4 * 66 * 34; i += 256) {
            int ic  = i / 2244;
            int rem = i - ic * 2244;
            int r = rem / 34, c = rem - r * 34;
            int gh = 2 * y0 - 1 + r, gw = 2 * x0 - 1 + c;
            float v = 0.f;
            if ((unsigned)gh < (unsigned)H && (unsigned)gw < (unsigned)W)
                v = __bfloat162float(in[((b * C + ic0 + ic) * H + gh) * W + gw]);
            sIn[ic][r][c] = v;
        }
        // stage weights (4*16*32 = 2048)
        for (int i = tid; i < 4 * 16 * 32; i += 256) {
            int ic  = i >> 9;
            int rem = i & 511;
            int tap = rem >> 5, o = rem & 31;
            sW[ic][tap][o] = dw[((oc0 + o) * C + ic0 + ic) * 16 + tap];
        }
        __syncthreads();

        for (int ic = 0; ic < 4; ++ic) {
            #pragma unroll
            for (int tap = 0; tap < 16; ++tap) {
                int kh = tap >> 2, kw = tap & 3;
                float in0 = sIn[ic][2 * ty + kh][2 * tx + kw];
                float in1 = sIn[ic][2 * ty + 32 + kh][2 * tx + kw];
                const float4* wp = (const float4*)&sW[ic][tap][0];
                #pragma unroll
                for (int o4 = 0; o4 < 8; ++o4) {
                    float4 w4 = wp[o4];
                    acc0[o4*4+0] += w4.x * in0;  acc1[o4*4+0] += w4.x * in1;
                    acc0[o4*4+1] += w4.y * in0;  acc1[o4*4+1] += w4.y * in1;
                    acc0[o4*4+2] += w4.z * in0;  acc1[o4*4+2] += w4.z * in1;
                    acc0[o4*4+3] += w4.w * in0;  acc1[o4*4+3] += w4.w * in1;
                }
            }
        }
    }

    int y = y0 + ty, x = x0 + tx;
    #pragma unroll
    for (int o = 0; o < 32; ++o) {
        float bias = db[oc0 + o];
        int idx0 = ((b * CO + oc0 + o) * HO + y) * WO + x;
        out[idx0]           = acc0[o] + bias;
        out[idx0 + 16 * WO] = acc1[o] + bias;
    }
}

// ---------------------------------------------------------------------------
extern "C" void kernel_launch(void* const* d_in, const int* in_sizes, int n_in,
                              void* d_out, int out_size, void* d_ws, size_t ws_size,
                              hipStream_t stream) {
    const float* features = (const float*)d_in[0];
    const float* sm1      = (const float*)d_in[1];   // style_mean1 -> s1
    const float* ss1      = (const float*)d_in[2];   // style_std1  -> s2 (per reference!)
    const float* w1       = (const float*)d_in[6];
    const float* w2       = (const float*)d_in[7];
    const float* dw       = (const float*)d_in[8];
    const float* db       = (const float*)d_in[9];
    float* out = (float*)d_out;

    char* ws = (char*)d_ws;
    __hip_bfloat16* x1 = (__hip_bfloat16*)ws;                       // 67,108,864 B
    __hip_bfloat16* x2 = (__hip_bfloat16*)(ws + 67108864);          // 67,108,864 B
    float* wm          = (float*)(ws + 134217728);                  // 2*9,437,184 B
    float* dvals       = (float*)(ws + 134217728 + 18874368);       // 16,384 B
    float* wm1 = wm;
    float* wm2 = wm + 2359296;

    demod_kernel <<<4096, 128, 0, stream>>>(w1, w2, sm1, ss1, dvals);
    expand_kernel<<<18432, 256, 0, stream>>>(w1, w2, sm1, ss1, dvals, wm);
    conv3x3_kernel<float>         <<<2048, 256, 0, stream>>>(features, wm1, nullptr, x1);
    conv3x3_kernel<__hip_bfloat16><<<2048, 256, 0, stream>>>(x1, wm2, x1, x2);
    downconv_kernel<<<1024, 256, 0, stream>>>(x2, dw, db, out);
}

// Round 2
// 807.430 us; speedup vs baseline: 4.9560x; 4.9560x over previous
//
#include <hip/hip_runtime.h>
#include <hip/hip_bf16.h>

constexpr int B  = 16;
constexpr int C  = 128;
constexpr int H  = 128;
constexpr int W  = 128;
constexpr int CO = 256;
constexpr int HO = 64;
constexpr int WO = 64;

#define EPSV   1e-8f
#define SLOPE  0.2f

typedef short bf16x8 __attribute__((ext_vector_type(8)));   // 8 bf16 in 4 VGPRs
typedef float f32x4  __attribute__((ext_vector_type(4)));

__device__ __forceinline__ short f2bs(float v) {
    __hip_bfloat16 h = __float2bfloat16(v);
    return *(short*)&h;
}
__device__ __forceinline__ float bs2f(short s) {
    __hip_bfloat16 h = *(__hip_bfloat16*)&s;
    return __bfloat162float(h);
}

// ---------------------------------------------------------------------------
// demod: d[conv][b][o] = rsqrt(sum_{i,k}(w[o,i,k]*(s[b,i]+1))^2 + eps)
// ---------------------------------------------------------------------------
__global__ __launch_bounds__(128) void demod_kernel(
    const float* __restrict__ w1, const float* __restrict__ w2,
    const float* __restrict__ s1, const float* __restrict__ s2,
    float* __restrict__ d)
{
    int bid  = blockIdx.x;          // conv*2048 + b*128 + o
    int conv = bid >> 11;
    int b    = (bid >> 7) & 15;
    int o    = bid & 127;
    const float* w = conv ? w2 : w1;
    const float* s = conv ? s2 : s1;
    int i = threadIdx.x;
    float sv = s[b * C + i] + 1.0f;
    const float* wp = w + (o * C + i) * 9;
    float sum = 0.f;
    #pragma unroll
    for (int k = 0; k < 9; ++k) { float t = wp[k] * sv; sum += t * t; }
    #pragma unroll
    for (int off = 32; off; off >>= 1) sum += __shfl_down(sum, off);
    __shared__ float red[2];
    if ((threadIdx.x & 63) == 0) red[threadIdx.x >> 6] = sum;
    __syncthreads();
    if (threadIdx.x == 0) d[bid] = rsqrtf(red[0] + red[1] + EPSV);
}

// ---------------------------------------------------------------------------
// expand: wm[conv][b][tap][oc][ic] (bf16)  = w*(s+1)*d
// total 2*16*9*128*128 = 4718592
// ---------------------------------------------------------------------------
__global__ __launch_bounds__(256) void expand_kernel(
    const float* __restrict__ w1, const float* __restrict__ w2,
    const float* __restrict__ s1, const float* __restrict__ s2,
    const float* __restrict__ d, short* __restrict__ wm)
{
    int idx = blockIdx.x * 256 + threadIdx.x;
    int ic  = idx & 127;
    int oc  = (idx >> 7) & 127;
    int t   = idx >> 14;            // (conv*16+b)*9+tap, < 288
    int tap = t % 9;
    int cb  = t / 9;                // conv*16+b
    int b   = cb & 15;
    int conv= cb >> 4;
    const float* w = conv ? w2 : w1;
    const float* s = conv ? s2 : s1;
    float v = w[(oc * C + ic) * 9 + tap] * (s[b * C + ic] + 1.0f)
            * d[(conv * B + b) * C + oc];
    wm[idx] = f2bs(v);
}

// ---------------------------------------------------------------------------
// dwexpand: dwm[tap16][oc256][ic128] (bf16) from dw[oc][ic][4][4]
// ---------------------------------------------------------------------------
__global__ __launch_bounds__(256) void dwexpand_kernel(
    const float* __restrict__ dw, short* __restrict__ dwm)
{
    int idx = blockIdx.x * 256 + threadIdx.x;   // 16*256*128 = 524288
    int ic  = idx & 127;
    int oc  = (idx >> 7) & 255;
    int tap = idx >> 15;
    dwm[idx] = f2bs(dw[(oc * C + ic) * 16 + tap]);
}

// ---------------------------------------------------------------------------
// nchw(f32) -> nhwc(bf16) transpose of features. block = one (b,h) row.
// ---------------------------------------------------------------------------
__global__ __launch_bounds__(256) void nchw2nhwc_kernel(
    const float* __restrict__ in, short* __restrict__ out)
{
    __shared__ short s[128 * 136];          // [w][ic pad 136]
    int bid = blockIdx.x;                   // b*128 + h
    int h = bid & 127, b = bid >> 7;
    int tid = threadIdx.x;
    for (int i = tid; i < 128 * 32; i += 256) {
        int w4 = i & 31, ic = i >> 5;
        float4 v = *(const float4*)&in[((b * C + ic) * H + h) * W + w4 * 4];
        s[(w4 * 4 + 0) * 136 + ic] = f2bs(v.x);
        s[(w4 * 4 + 1) * 136 + ic] = f2bs(v.y);
        s[(w4 * 4 + 2) * 136 + ic] = f2bs(v.z);
        s[(w4 * 4 + 3) * 136 + ic] = f2bs(v.w);
    }
    __syncthreads();
    for (int i = tid; i < 128 * 16; i += 256) {
        int icg = i & 15, w = i >> 4;
        *(uint4*)&out[((b * H + h) * W + w) * C + icg * 8] =
            *(uint4*)&s[w * 136 + icg * 8];
    }
}

// ---------------------------------------------------------------------------
// conv3x3 MFMA implicit GEMM. in: NHWC bf16. out: NHWC bf16.
// block tile: 128 px (8h x 16w) x 128 oc. 4 waves, each 64 px x 64 oc.
// K = 9 taps x 128 ic (4 chunks of 32).
// A = input (m = w-pixel), B = weights wm[b][tap][oc][ic].
// ---------------------------------------------------------------------------
__global__ __launch_bounds__(256, 3) void conv3x3_mfma(
    const short* __restrict__ in, const short* __restrict__ wmc,
    const short* __restrict__ res, short* __restrict__ out)
{
    __shared__ short sIn[10 * 18 * 136];   // rows h0-1..h0+8, w0-1..w0+16, 128ic pad136

    int bid = blockIdx.x;
    int wt = bid & 7, ht = (bid >> 3) & 15, b = bid >> 7;
    int w0 = wt * 16, h0 = ht * 8;
    int tid  = threadIdx.x;
    int lane = tid & 63, wv = tid >> 6;
    int q = lane >> 4, l15 = lane & 15;
    int wr = wv & 1;       // row half: rows h0 + wr*4 .. +3
    int wc = wv >> 1;      // oc half:  oc  wc*64 .. +63

    // stage input tile: 10*18 pixels x 16 x (8 bf16) groups
    for (int i = tid; i < 10 * 18 * 16; i += 256) {
        int icg = i & 15;
        int t = i >> 4;
        int wl = t % 18, hl = t / 18;
        int gh = h0 - 1 + hl, gw = w0 - 1 + wl;
        uint4 v = make_uint4(0u, 0u, 0u, 0u);
        if ((unsigned)gh < (unsigned)H && (unsigned)gw < (unsigned)W)
            v = *(const uint4*)&in[((b * H + gh) * W + gw) * C + icg * 8];
        *(uint4*)&sIn[(hl * 18 + wl) * 136 + icg * 8] = v;
    }
    __syncthreads();

    const short* wb = wmc + b * (9 * 128 * 128);

    f32x4 acc[4][4];   // [mt = h-row][nt = oc tile]
    #pragma unroll
    for (int mt = 0; mt < 4; ++mt)
        #pragma unroll
        for (int nt = 0; nt < 4; ++nt)
            acc[mt][nt] = (f32x4){0.f, 0.f, 0.f, 0.f};

    for (int tap = 0; tap < 9; ++tap) {
        int dh = tap / 3, dw = tap - dh * 3;
        #pragma unroll
        for (int c = 0; c < 4; ++c) {
            bf16x8 af[4], bf[4];
            #pragma unroll
            for (int mt = 0; mt < 4; ++mt)
                af[mt] = *(const bf16x8*)&sIn[((wr * 4 + mt + dh) * 18 + l15 + dw) * 136
                                              + c * 32 + q * 8];
            #pragma unroll
            for (int nt = 0; nt < 4; ++nt)
                bf[nt] = *(const bf16x8*)&wb[(tap * 128 + wc * 64 + nt * 16 + l15) * 128
                                             + c * 32 + q * 8];
            #pragma unroll
            for (int mt = 0; mt < 4; ++mt)
                #pragma unroll
                for (int nt = 0; nt < 4; ++nt)
                    acc[mt][nt] = __builtin_amdgcn_mfma_f32_16x16x32_bf16(
                        af[mt], bf[nt], acc[mt][nt], 0, 0, 0);
        }
    }

    // epilogue: D col = oc offset (l15), row = w offset (q*4+reg)
    bool has_res = (res != nullptr);
    #pragma unroll
    for (int mt = 0; mt < 4; ++mt) {
        int h = h0 + wr * 4 + mt;
        #pragma unroll
        for (int nt = 0; nt < 4; ++nt) {
            int oc = wc * 64 + nt * 16 + l15;
            #pragma unroll
            for (int reg = 0; reg < 4; ++reg) {
                int w = w0 + q * 4 + reg;
                int idx = ((b * H + h) * W + w) * C + oc;
                float v = acc[mt][nt][reg];
                if (has_res) v += bs2f(res[idx]);
                v = v >= 0.f ? v : SLOPE * v;
                out[idx] = f2bs(v);
            }
        }
    }
}

// ---------------------------------------------------------------------------
// downconv MFMA: 4x4 stride2 pad1, in NHWC bf16 x2, out NCHW fp32 + bias.
// block tile: 128 out px (8 oh x 16 ow) x 128 oc. 4 waves, each 64oc x 64px.
// A = weights dwm[tap][oc][ic] (m = oc), B = input (n = ow pixel).
// input chunk staged per 32 ic, even/odd-w deinterleaved: [h19][par2][w2 18][40]
// ---------------------------------------------------------------------------
__global__ __launch_bounds__(256, 2) void downconv_mfma(
    const short* __restrict__ in, const short* __restrict__ dwm,
    const float* __restrict__ db, float* __restrict__ out)
{
    __shared__ short sIn[19 * 2 * 18 * 40];   // 54720 B

    int bid = blockIdx.x;
    int wt = bid & 3;  bid >>= 2;    // ow tile (4)
    int ht = bid & 7;  bid >>= 3;    // oh tile (8)
    int ot = bid & 1;  bid >>= 1;    // oc tile (2)
    int b  = bid;
    int ow0 = wt * 16, oh0 = ht * 8, oc0 = ot * 128;

    int tid  = threadIdx.x;
    int lane = tid & 63, wv = tid >> 6;
    int q = lane >> 4, l15 = lane & 15;
    int wo = wv & 1;     // oc half within block tile
    int wp = wv >> 1;    // px half: oh rows oh0 + wp*4 + nt

    f32x4 acc[4][4];     // [mt = oc tile][nt = oh row]
    #pragma unroll
    for (int mt = 0; mt < 4; ++mt)
        #pragma unroll
        for (int nt = 0; nt < 4; ++nt)
            acc[mt][nt] = (f32x4){0.f, 0.f, 0.f, 0.f};

    for (int c = 0; c < 4; ++c) {
        __syncthreads();
        // stage 19x35 px x 4 x (8 bf16) of ic chunk c
        for (int i = tid; i < 19 * 35 * 4; i += 256) {
            int icg = i & 3;
            int t = i >> 2;
            int wl = t % 35, hl = t / 35;
            int gh = 2 * oh0 - 1 + hl, gw = 2 * ow0 - 1 + wl;
            uint4 v = make_uint4(0u, 0u, 0u, 0u);
            if ((unsigned)gh < (unsigned)H && (unsigned)gw < (unsigned)W)
                v = *(const uint4*)&in[((b * H + gh) * W + gw) * C + c * 32 + icg * 8];
            *(uint4*)&sIn[((hl * 2 + (wl & 1)) * 18 + (wl >> 1)) * 40 + icg * 8] = v;
        }
        __syncthreads();

        for (int tap = 0; tap < 16; ++tap) {
            int dh = tap >> 2, dw = tap & 3;
            bf16x8 af[4], bf[4];
            #pragma unroll
            for (int mt = 0; mt < 4; ++mt)
                af[mt] = *(const bf16x8*)&dwm[(tap * 256 + oc0 + wo * 64 + mt * 16 + l15) * 128
                                              + c * 32 + q * 8];
            #pragma unroll
            for (int nt = 0; nt < 4; ++nt) {
                int hl = 2 * (wp * 4 + nt) + dh;
                bf[nt] = *(const bf16x8*)&sIn[((hl * 2 + (dw & 1)) * 18 + l15 + (dw >> 1)) * 40
                                              + q * 8];
            }
            #pragma unroll
            for (int mt = 0; mt < 4; ++mt)
                #pragma unroll
                for (int nt = 0; nt < 4; ++nt)
                    acc[mt][nt] = __builtin_amdgcn_mfma_f32_16x16x32_bf16(
                        af[mt], bf[nt], acc[mt][nt], 0, 0, 0);
        }
    }

    // epilogue: D row = oc offset (q*4+reg), col = ow offset (l15)
    #pragma unroll
    for (int mt = 0; mt < 4; ++mt) {
        #pragma unroll
        for (int reg = 0; reg < 4; ++reg) {
            int oc = oc0 + wo * 64 + mt * 16 + q * 4 + reg;
            float bias = db[oc];
            #pragma unroll
            for (int nt = 0; nt < 4; ++nt) {
                int oh = oh0 + wp * 4 + nt;
                int ow = ow0 + l15;
                out[((b * CO + oc) * HO + oh) * WO + ow] = acc[mt][nt][reg] + bias;
            }
        }
    }
}

// ---------------------------------------------------------------------------
extern "C" void kernel_launch(void* const* d_in, const int* in_sizes, int n_in,
                              void* d_out, int out_size, void* d_ws, size_t ws_size,
                              hipStream_t stream) {
    const float* features = (const float*)d_in[0];
    const float* sm1      = (const float*)d_in[1];   // style_mean1 -> s1
    const float* ss1      = (const float*)d_in[2];   // style_std1  -> s2 (per reference)
    const float* w1       = (const float*)d_in[6];
    const float* w2       = (const float*)d_in[7];
    const float* dw       = (const float*)d_in[8];
    const float* db       = (const float*)d_in[9];
    float* out = (float*)d_out;

    char* ws = (char*)d_ws;
    short* x1  = (short*)ws;                              // 67,108,864 B
    short* x2  = (short*)(ws + 67108864);                 // 67,108,864 B (also fx)
    short* wm  = (short*)(ws + 134217728);                // 9,437,184 B
    short* dwm = (short*)(ws + 143654912);                // 1,048,576 B
    float* dv  = (float*)(ws + 144703488);                // 16,384 B

    demod_kernel   <<<4096, 128, 0, stream>>>(w1, w2, sm1, ss1, dv);
    expand_kernel  <<<18432, 256, 0, stream>>>(w1, w2, sm1, ss1, dv, wm);
    dwexpand_kernel<<<2048, 256, 0, stream>>>(dw, dwm);
    nchw2nhwc_kernel<<<2048, 256, 0, stream>>>(features, x2);   // fx lives in x2
    conv3x3_mfma   <<<2048, 256, 0, stream>>>(x2, wm, nullptr, x1);
    conv3x3_mfma   <<<2048, 256, 0, stream>>>(x1, wm + 16 * 9 * 128 * 128, x1, x2);
    downconv_mfma  <<<1024, 256, 0, stream>>>(x2, dwm, db, out);
}

// Round 3
// 691.677 us; speedup vs baseline: 5.7854x; 1.1674x over previous
//
#include <hip/hip_runtime.h>
#include <hip/hip_bf16.h>

constexpr int B  = 16;
constexpr int C  = 128;
constexpr int H  = 128;
constexpr int W  = 128;
constexpr int CO = 256;
constexpr int HO = 64;
constexpr int WO = 64;

#define EPSV   1e-8f
#define SLOPE  0.2f

typedef short bf16x8 __attribute__((ext_vector_type(8)));
typedef float f32x4  __attribute__((ext_vector_type(4)));

__device__ __forceinline__ short f2bs(float v) {
    __hip_bfloat16 h = __float2bfloat16(v);
    return *(short*)&h;
}
__device__ __forceinline__ float bs2f(short s) {
    __hip_bfloat16 h = *(__hip_bfloat16*)&s;
    return __bfloat162float(h);
}

// ---------------------------------------------------------------------------
// demod: d[conv][b][o] = rsqrt(sum_{i,k}(w[o,i,k]*(s[b,i]+1))^2 + eps)
// ---------------------------------------------------------------------------
__global__ __launch_bounds__(128) void demod_kernel(
    const float* __restrict__ w1, const float* __restrict__ w2,
    const float* __restrict__ s1, const float* __restrict__ s2,
    float* __restrict__ d)
{
    int bid  = blockIdx.x;          // conv*2048 + b*128 + o
    int conv = bid >> 11;
    int b    = (bid >> 7) & 15;
    int o    = bid & 127;
    const float* w = conv ? w2 : w1;
    const float* s = conv ? s2 : s1;
    int i = threadIdx.x;
    float sv = s[b * C + i] + 1.0f;
    const float* wp = w + (o * C + i) * 9;
    float sum = 0.f;
    #pragma unroll
    for (int k = 0; k < 9; ++k) { float t = wp[k] * sv; sum += t * t; }
    #pragma unroll
    for (int off = 32; off; off >>= 1) sum += __shfl_down(sum, off);
    __shared__ float red[2];
    if ((threadIdx.x & 63) == 0) red[threadIdx.x >> 6] = sum;
    __syncthreads();
    if (threadIdx.x == 0) d[bid] = rsqrtf(red[0] + red[1] + EPSV);
}

// ---------------------------------------------------------------------------
// expand -> wave-coalesced B-fragment tiling:
// wm[cb][tap][ocT=oc>>4][icC=ic>>5][(oc&15)*32 + (ic&31)]   (bf16)
// one fragment (tap,ocT,icC) = 512 elems = 1KB contiguous; lane reads
// l15*32 + q*8 -> perfectly coalesced per wave.
// ---------------------------------------------------------------------------
__global__ __launch_bounds__(256) void expand_kernel(
    const float* __restrict__ w1, const float* __restrict__ w2,
    const float* __restrict__ s1, const float* __restrict__ s2,
    const float* __restrict__ d, short* __restrict__ wm)
{
    int idx = blockIdx.x * 256 + threadIdx.x;
    int ic  = idx & 127;
    int oc  = (idx >> 7) & 127;
    int t   = idx >> 14;            // cb*9+tap, < 288
    int tap = t % 9;
    int cb  = t / 9;                // conv*16+b
    int b   = cb & 15;
    int conv= cb >> 4;
    const float* w = conv ? w2 : w1;
    const float* s = conv ? s2 : s1;
    float v = w[(oc * C + ic) * 9 + tap] * (s[b * C + ic] + 1.0f)
            * d[(conv * B + b) * C + oc];
    int dst = cb * 147456
            + ((tap * 8 + (oc >> 4)) * 4 + (ic >> 5)) * 512
            + (oc & 15) * 32 + (ic & 31);
    wm[dst] = f2bs(v);
}

// ---------------------------------------------------------------------------
// dwexpand: dwm[tap][ocT=oc>>4 (16)][icC=ic>>5 (4)][(oc&15)*32+(ic&31)]
// ---------------------------------------------------------------------------
__global__ __launch_bounds__(256) void dwexpand_kernel(
    const float* __restrict__ dw, short* __restrict__ dwm)
{
    int idx = blockIdx.x * 256 + threadIdx.x;   // 16*256*128 = 524288
    int ic  = idx & 127;
    int oc  = (idx >> 7) & 255;
    int tap = idx >> 15;
    int dst = ((tap * 16 + (oc >> 4)) * 4 + (ic >> 5)) * 512
            + (oc & 15) * 32 + (ic & 31);
    dwm[dst] = f2bs(dw[(oc * C + ic) * 16 + tap]);
}

// ---------------------------------------------------------------------------
// nchw(f32) -> nhwc(bf16) transpose of features.
// ---------------------------------------------------------------------------
__global__ __launch_bounds__(256) void nchw2nhwc_kernel(
    const float* __restrict__ in, short* __restrict__ out)
{
    __shared__ short s[128 * 136];
    int bid = blockIdx.x;                   // b*128 + h
    int h = bid & 127, b = bid >> 7;
    int tid = threadIdx.x;
    for (int i = tid; i < 128 * 32; i += 256) {
        int w4 = i & 31, ic = i >> 5;
        float4 v = *(const float4*)&in[((b * C + ic) * H + h) * W + w4 * 4];
        s[(w4 * 4 + 0) * 136 + ic] = f2bs(v.x);
        s[(w4 * 4 + 1) * 136 + ic] = f2bs(v.y);
        s[(w4 * 4 + 2) * 136 + ic] = f2bs(v.z);
        s[(w4 * 4 + 3) * 136 + ic] = f2bs(v.w);
    }
    __syncthreads();
    for (int i = tid; i < 128 * 16; i += 256) {
        int icg = i & 15, w = i >> 4;
        *(uint4*)&out[((b * H + h) * W + w) * C + icg * 8] =
            *(uint4*)&s[w * 136 + icg * 8];
    }
}

// ---------------------------------------------------------------------------
// conv3x3 MFMA implicit GEMM, register-double-buffered K pipeline.
// block tile: 128 px (8h x 16w) x 128 oc; wave: 64 px x 64 oc.
// K steps: 9 taps x 4 ic-chunks = 36; prefetch step s+1 during MFMAs of s.
// ---------------------------------------------------------------------------
__global__ __launch_bounds__(256, 3) void conv3x3_mfma(
    const short* __restrict__ in, const short* __restrict__ wmc,
    const short* __restrict__ res, short* __restrict__ out)
{
    __shared__ short sIn[10 * 18 * 136];   // 48,960 B

    int bid = blockIdx.x;
    int wt = bid & 7, ht = (bid >> 3) & 15, b = bid >> 7;
    int w0 = wt * 16, h0 = ht * 8;
    int tid  = threadIdx.x;
    int lane = tid & 63, wv = tid >> 6;
    int q = lane >> 4, l15 = lane & 15;
    int wr = wv & 1;       // row half
    int wc = wv >> 1;      // oc half

    for (int i = tid; i < 10 * 18 * 16; i += 256) {
        int icg = i & 15;
        int t = i >> 4;
        int wl = t % 18, hl = t / 18;
        int gh = h0 - 1 + hl, gw = w0 - 1 + wl;
        uint4 v = make_uint4(0u, 0u, 0u, 0u);
        if ((unsigned)gh < (unsigned)H && (unsigned)gw < (unsigned)W)
            v = *(const uint4*)&in[((b * H + gh) * W + gw) * C + icg * 8];
        *(uint4*)&sIn[(hl * 18 + wl) * 136 + icg * 8] = v;
    }
    __syncthreads();

    const short* wb = wmc + b * 147456;

    f32x4 acc[4][4];
    #pragma unroll
    for (int mt = 0; mt < 4; ++mt)
        #pragma unroll
        for (int nt = 0; nt < 4; ++nt)
            acc[mt][nt] = (f32x4){0.f, 0.f, 0.f, 0.f};

    bf16x8 af[2][4], bf[2][4];

    // prologue: (tap=0 -> dh=0,dw=0, c=0) into parity 0
    #pragma unroll
    for (int mt = 0; mt < 4; ++mt)
        af[0][mt] = *(const bf16x8*)&sIn[((wr * 4 + mt) * 18 + l15) * 136 + q * 8];
    #pragma unroll
    for (int nt = 0; nt < 4; ++nt)
        bf[0][nt] = *(const bf16x8*)&wb[((0 * 8 + wc * 4 + nt) * 4 + 0) * 512
                                        + l15 * 32 + q * 8];

    #pragma unroll 1
    for (int tap = 0; tap < 9; ++tap) {
        int dh  = tap / 3,  dwd = tap - dh * 3;
        int tapn = (tap + 1 < 9) ? tap + 1 : tap;   // dummy prefetch on last
        int dhn = tapn / 3, dwn = tapn - dhn * 3;
        #pragma unroll
        for (int c = 0; c < 4; ++c) {
            int p  = c & 1, pn = p ^ 1;
            int cn = (c + 1) & 3;
            int tE  = (c == 3) ? tapn : tap;
            int dhE = (c == 3) ? dhn : dh;
            int dwE = (c == 3) ? dwn : dwd;
            // prefetch step s+1
            #pragma unroll
            for (int mt = 0; mt < 4; ++mt)
                af[pn][mt] = *(const bf16x8*)&sIn[((wr * 4 + mt + dhE) * 18 + l15 + dwE) * 136
                                                  + cn * 32 + q * 8];
            #pragma unroll
            for (int nt = 0; nt < 4; ++nt)
                bf[pn][nt] = *(const bf16x8*)&wb[((tE * 8 + wc * 4 + nt) * 4 + cn) * 512
                                                 + l15 * 32 + q * 8];
            // compute step s
            #pragma unroll
            for (int mt = 0; mt < 4; ++mt)
                #pragma unroll
                for (int nt = 0; nt < 4; ++nt)
                    acc[mt][nt] = __builtin_amdgcn_mfma_f32_16x16x32_bf16(
                        af[p][mt], bf[p][nt], acc[mt][nt], 0, 0, 0);
        }
    }

    bool has_res = (res != nullptr);
    #pragma unroll
    for (int mt = 0; mt < 4; ++mt) {
        int h = h0 + wr * 4 + mt;
        #pragma unroll
        for (int nt = 0; nt < 4; ++nt) {
            int oc = wc * 64 + nt * 16 + l15;
            #pragma unroll
            for (int reg = 0; reg < 4; ++reg) {
                int w = w0 + q * 4 + reg;
                int idx = ((b * H + h) * W + w) * C + oc;
                float v = acc[mt][nt][reg];
                if (has_res) v += bs2f(res[idx]);
                v = v >= 0.f ? v : SLOPE * v;
                out[idx] = f2bs(v);
            }
        }
    }
}

// ---------------------------------------------------------------------------
// downconv MFMA, register-double-buffered over the 16-tap loop per ic-chunk.
// A = weights dwm (global, tiled), B = input (LDS, stride-2 deinterleaved).
// ---------------------------------------------------------------------------
__global__ __launch_bounds__(256, 2) void downconv_mfma(
    const short* __restrict__ in, const short* __restrict__ dwm,
    const float* __restrict__ db, float* __restrict__ out)
{
    __shared__ short sIn[19 * 2 * 18 * 40];   // 54,720 B

    int bid = blockIdx.x;
    int wt = bid & 3;  bid >>= 2;
    int ht = bid & 7;  bid >>= 3;
    int ot = bid & 1;  bid >>= 1;
    int b  = bid;
    int ow0 = wt * 16, oh0 = ht * 8, oc0 = ot * 128;

    int tid  = threadIdx.x;
    int lane = tid & 63, wv = tid >> 6;
    int q = lane >> 4, l15 = lane & 15;
    int wo = wv & 1;
    int wp = wv >> 1;

    f32x4 acc[4][4];
    #pragma unroll
    for (int mt = 0; mt < 4; ++mt)
        #pragma unroll
        for (int nt = 0; nt < 4; ++nt)
            acc[mt][nt] = (f32x4){0.f, 0.f, 0.f, 0.f};

    int ocTb = ot * 8 + wo * 4;   // this wave's oc-tile base (16-oc units)

    for (int c = 0; c < 4; ++c) {
        __syncthreads();
        for (int i = tid; i < 19 * 35 * 4; i += 256) {
            int icg = i & 3;
            int t = i >> 2;
            int wl = t % 35, hl = t / 35;
            int gh = 2 * oh0 - 1 + hl, gw = 2 * ow0 - 1 + wl;
            uint4 v = make_uint4(0u, 0u, 0u, 0u);
            if ((unsigned)gh < (unsigned)H && (unsigned)gw < (unsigned)W)
                v = *(const uint4*)&in[((b * H + gh) * W + gw) * C + c * 32 + icg * 8];
            *(uint4*)&sIn[((hl * 2 + (wl & 1)) * 18 + (wl >> 1)) * 40 + icg * 8] = v;
        }
        __syncthreads();

        bf16x8 af[2][4], bf[2][4];
        // prologue: tap 0 (dh=0, dw=0)
        #pragma unroll
        for (int mt = 0; mt < 4; ++mt)
            af[0][mt] = *(const bf16x8*)&dwm[((0 * 16 + ocTb + mt) * 4 + c) * 512
                                             + l15 * 32 + q * 8];
        #pragma unroll
        for (int nt = 0; nt < 4; ++nt) {
            int hl = 2 * (wp * 4 + nt);
            bf[0][nt] = *(const bf16x8*)&sIn[((hl * 2 + 0) * 18 + l15 + 0) * 40 + q * 8];
        }

        #pragma unroll
        for (int tap = 0; tap < 16; ++tap) {
            int p = tap & 1, pn = p ^ 1;
            int tapn = (tap + 1 < 16) ? tap + 1 : tap;
            int dhn = tapn >> 2, dwn = tapn & 3;
            // prefetch tap+1
            #pragma unroll
            for (int mt = 0; mt < 4; ++mt)
                af[pn][mt] = *(const bf16x8*)&dwm[((tapn * 16 + ocTb + mt) * 4 + c) * 512
                                                  + l15 * 32 + q * 8];
            #pragma unroll
            for (int nt = 0; nt < 4; ++nt) {
                int hl = 2 * (wp * 4 + nt) + dhn;
                bf[pn][nt] = *(const bf16x8*)&sIn[((hl * 2 + (dwn & 1)) * 18 + l15 + (dwn >> 1)) * 40
                                                  + q * 8];
            }
            // compute tap
            #pragma unroll
            for (int mt = 0; mt < 4; ++mt)
                #pragma unroll
                for (int nt = 0; nt < 4; ++nt)
                    acc[mt][nt] = __builtin_amdgcn_mfma_f32_16x16x32_bf16(
                        af[p][mt], bf[p][nt], acc[mt][nt], 0, 0, 0);
        }
    }

    #pragma unroll
    for (int mt = 0; mt < 4; ++mt) {
        #pragma unroll
        for (int reg = 0; reg < 4; ++reg) {
            int oc = oc0 + wo * 64 + mt * 16 + q * 4 + reg;
            float bias = db[oc];
            #pragma unroll
            for (int nt = 0; nt < 4; ++nt) {
                int oh = oh0 + wp * 4 + nt;
                int ow = ow0 + l15;
                out[((b * CO + oc) * HO + oh) * WO + ow] = acc[mt][nt][reg] + bias;
            }
        }
    }
}

// ---------------------------------------------------------------------------
extern "C" void kernel_launch(void* const* d_in, const int* in_sizes, int n_in,
                              void* d_out, int out_size, void* d_ws, size_t ws_size,
                              hipStream_t stream) {
    const float* features = (const float*)d_in[0];
    const float* sm1      = (const float*)d_in[1];   // style_mean1 -> s1
    const float* ss1      = (const float*)d_in[2];   // style_std1  -> s2 (per reference)
    const float* w1       = (const float*)d_in[6];
    const float* w2       = (const float*)d_in[7];
    const float* dw       = (const float*)d_in[8];
    const float* db       = (const float*)d_in[9];
    float* out = (float*)d_out;

    char* ws = (char*)d_ws;
    short* x1  = (short*)ws;                              // 67,108,864 B
    short* x2  = (short*)(ws + 67108864);                 // 67,108,864 B (also fx)
    short* wm  = (short*)(ws + 134217728);                // 9,437,184 B
    short* dwm = (short*)(ws + 143654912);                // 1,048,576 B
    float* dv  = (float*)(ws + 144703488);                // 16,384 B

    demod_kernel    <<<4096, 128, 0, stream>>>(w1, w2, sm1, ss1, dv);
    expand_kernel   <<<18432, 256, 0, stream>>>(w1, w2, sm1, ss1, dv, wm);
    dwexpand_kernel <<<2048, 256, 0, stream>>>(dw, dwm);
    nchw2nhwc_kernel<<<2048, 256, 0, stream>>>(features, x2);
    conv3x3_mfma    <<<2048, 256, 0, stream>>>(x2, wm, nullptr, x1);
    conv3x3_mfma    <<<2048, 256, 0, stream>>>(x1, wm + 16 * 147456, x1, x2);
    downconv_mfma   <<<1024, 256, 0, stream>>>(x2, dwm, db, out);
}